// Round 3
// baseline (334.638 us; speedup 1.0000x reference)
//
#include <hip/hip_runtime.h>
#include <stdint.h>

// xxh32 primes
#define XP2 2246822519u
#define XP3 3266489917u
#define XP4 668265263u
#define XP5 374761393u

constexpr int EMB_LEVELS = 1000000;
constexpr int F = 20;
constexpr int UNROLL = 4;

typedef float f32x4 __attribute__((ext_vector_type(4)));

__device__ __forceinline__ uint32_t rotl32(uint32_t v, int r) {
    return (v << r) | (v >> (32 - r));
}

__device__ __forceinline__ uint32_t xxh32_4(uint32_t val, uint32_t seed) {
    uint32_t acc = seed + XP5 + 4u;
    acc += val * XP3;
    acc = rotl32(acc, 17) * XP4;
    acc ^= acc >> 15;
    acc *= XP2;
    acc ^= acc >> 13;
    acc *= XP3;
    acc ^= acc >> 16;
    return acc;
}

// Unit = one float4 of one (n,f) pair's embedding row: 16 units per pair.
// Grid-stride with 4-way ILP: issue 4 independent gather loads before any use
// -> 4x memory-level parallelism per wave vs the one-shot version.
__global__ __launch_bounds__(256) void ue_kernel(
    const int* __restrict__ x,
    const int* __restrict__ fnum,
    const f32x4* __restrict__ emb,    // [EMB_LEVELS * 16] float4
    f32x4* __restrict__ out,          // [total_pairs * 16] float4
    int total_units)                  // total_pairs * 16
{
    const int stride = gridDim.x * blockDim.x;
    const int t0 = blockIdx.x * blockDim.x + threadIdx.x;

    for (int base = t0; base < total_units; base += stride * UNROLL) {
        f32x4 v[UNROLL];
        int   tu[UNROLL];
        bool  ok[UNROLL];

        #pragma unroll
        for (int u = 0; u < UNROLL; u++) {
            int t = base + u * stride;
            ok[u] = (t < total_units);
            tu[u] = t;
            if (ok[u]) {
                int pair = t >> 4;
                int lane = t & 15;
                int n = pair / F;
                int f = pair - n * F;
                uint32_t h = xxh32_4((uint32_t)x[n], (uint32_t)fnum[f]);
                uint32_t idx = h % (uint32_t)EMB_LEVELS;
                v[u] = emb[(size_t)idx * 16 + lane];   // 4 loads in flight
            }
        }

        #pragma unroll
        for (int u = 0; u < UNROLL; u++) {
            if (ok[u]) {
                // output has zero reuse -> non-temporal, keep L2/L3 for emb
                __builtin_nontemporal_store(v[u], &out[(size_t)tu[u]]);
            }
        }
    }
}

extern "C" void kernel_launch(void* const* d_in, const int* in_sizes, int n_in,
                              void* d_out, int out_size, void* d_ws, size_t ws_size,
                              hipStream_t stream) {
    const int*   x    = (const int*)d_in[0];     // [N] int32
    const int*   fnum = (const int*)d_in[1];     // [F] int32
    const float* emb  = (const float*)d_in[2];   // [EMB_LEVELS, 64] f32
    float*       out  = (float*)d_out;           // [N, F*64] f32

    int n_rows = in_sizes[0];                    // N = 16384
    int total_pairs = n_rows * F;                // 327,680
    int total_units = total_pairs * 16;          // 5,242,880

    int block = 256;
    int grid  = 2560;    // 10 blocks/CU worth of grid-stride work

    ue_kernel<<<grid, block, 0, stream>>>(
        x, fnum, (const f32x4*)emb, (f32x4*)out, total_units);
}